// Round 1
// baseline (12254.055 us; speedup 1.0000x reference)
//
#include <hip/hip_runtime.h>
#include <cstddef>

#define LRr 0.02f

enum { EPI_RAW = 0, EPI_E = 1, EPI_P2 = 2, EPI_P3 = 3 };

// Direct 3x3 conv, padding=1. Block = 256 threads covering IMGS images x TILE^2 pixels.
// Stages CI_STEP input channel planes (with halo) in LDS per step; weights are
// block-uniform -> scalar loads. Each thread accumulates NCO output channels.
template<int HIN, int CIN, int COUT, int NCO, int TILE, int IMGS, int CI_STEP, int EPI, bool TR>
__global__ __launch_bounds__(256)
void convk(const float* __restrict__ in, const float* __restrict__ wgt,
           float* __restrict__ out, const float* __restrict__ aux, float* __restrict__ rr)
{
  constexpr int TILES = HIN / TILE;
  constexpr int CO_GRPS = COUT / NCO;
  constexpr int PW = TILE + 2;
  constexpr int PLANE = PW * PW;
  constexpr int CHUNK = CI_STEP * IMGS * PLANE;

  __shared__ float slds[CHUNK];

  const int bid = blockIdx.x;
  const int co_grp = bid % CO_GRPS;
  const int t2 = bid / CO_GRPS;
  const int tile_id = t2 % (TILES * TILES);
  const int img_grp = t2 / (TILES * TILES);
  const int ty0 = (tile_id / TILES) * TILE;
  const int tx0 = (tile_id % TILES) * TILE;
  const int co0 = co_grp * NCO;

  const int tid = threadIdx.x;
  const int im = (IMGS > 1) ? (tid / (TILE * TILE)) : 0;
  const int p  = (IMGS > 1) ? (tid % (TILE * TILE)) : tid;
  const int ty = p / TILE, tx = p % TILE;
  const int b = img_grp * IMGS + im;

  float acc[NCO];
#pragma unroll
  for (int k = 0; k < NCO; ++k) acc[k] = 0.f;

  for (int ci0 = 0; ci0 < CIN; ci0 += CI_STEP) {
    __syncthreads();
    for (int l = tid; l < CHUNK; l += 256) {
      const int x = l % PW;
      const int y = (l / PW) % PW;
      const int imcc = l / PLANE;
      const int im2 = imcc % IMGS;
      const int cc = imcc / IMGS;
      const int gy = ty0 + y - 1, gx = tx0 + x - 1;
      float v = 0.f;
      if (gy >= 0 && gy < HIN && gx >= 0 && gx < HIN)
        v = in[(((size_t)(img_grp * IMGS + im2) * CIN + (ci0 + cc)) * HIN + gy) * HIN + gx];
      slds[l] = v;
    }
    __syncthreads();
#pragma unroll
    for (int cc = 0; cc < CI_STEP; ++cc) {
      const float* pl = slds + (cc * IMGS + im) * PLANE;
      const int ci = ci0 + cc;
#pragma unroll
      for (int dy = 0; dy < 3; ++dy) {
#pragma unroll
        for (int dx = 0; dx < 3; ++dx) {
          const float v = pl[(ty + dy) * PW + (tx + dx)];
#pragma unroll
          for (int k = 0; k < NCO; ++k) {
            const int co = co0 + k;
            const float w = TR
              ? wgt[(((size_t)ci * COUT + co) * 3 + (2 - dy)) * 3 + (2 - dx)]
              : wgt[(((size_t)co * CIN + ci) * 3 + dy) * 3 + dx];
            acc[k] = fmaf(v, w, acc[k]);
          }
        }
      }
    }
  }

  const int gy = ty0 + ty, gx = tx0 + tx;

  if constexpr (EPI == EPI_RAW) {
#pragma unroll
    for (int k = 0; k < NCO; ++k)
      out[(((size_t)b * COUT + (co0 + k)) * HIN + gy) * HIN + gx] = acc[k];
  } else if constexpr (EPI == EPI_E) {
    // e = aux(r, at 2x resolution) - tanh(upsampled conv result)
    constexpr int H2 = HIN * 2;
#pragma unroll
    for (int k = 0; k < NCO; ++k) {
      const float tv = tanhf(acc[k]);
      const size_t base = ((size_t)b * COUT + (co0 + k)) * (H2 * H2);
#pragma unroll
      for (int dy = 0; dy < 2; ++dy) {
#pragma unroll
        for (int dx = 0; dx < 2; ++dx) {
          const size_t idx = base + (size_t)(2 * gy + dy) * H2 + (2 * gx + dx);
          out[idx] = aux[idx] - tv;
        }
      }
    }
  } else if constexpr (EPI == EPI_P2) {
    // avgpool 2x2 via shfl, then r2 = relu(r2 + LR*(-e2 + pooled))
    constexpr int HP = HIN / 2;
#pragma unroll
    for (int k = 0; k < NCO; ++k) {
      float s = acc[k] + __shfl_xor(acc[k], 1);
      s += __shfl_xor(s, TILE);
      if (((tx & 1) | (ty & 1)) == 0) {
        const size_t idx = (((size_t)b * COUT + (co0 + k)) * HP + (gy >> 1)) * HP + (gx >> 1);
        const float dr = 0.25f * s - aux[idx];
        rr[idx] = fmaxf(fmaf(LRr, dr, rr[idx]), 0.f);
      }
    }
  } else { // EPI_P3: r3 = relu(r3 + LR*pooled)
    constexpr int HP = HIN / 2;
#pragma unroll
    for (int k = 0; k < NCO; ++k) {
      float s = acc[k] + __shfl_xor(acc[k], 1);
      s += __shfl_xor(s, TILE);
      if (((tx & 1) | (ty & 1)) == 0) {
        const size_t idx = (((size_t)b * COUT + (co0 + k)) * HP + (gy >> 1)) * HP + (gx >> 1);
        rr[idx] = fmaxf(fmaf(LRr, 0.25f * s, rr[idx]), 0.f);
      }
    }
  }
}

// Per-channel sum / sumsq reduction over [B, C, HW]; grid = C * 8 chunks of 32 images.
template<int C, int HW>
__global__ __launch_bounds__(256)
void stats_k(const float* __restrict__ t, float* __restrict__ sums)
{
  const int c = blockIdx.x % C;
  const int chunk = blockIdx.x / C;
  float s1 = 0.f, s2 = 0.f;
  for (int bb = 0; bb < 32; ++bb) {
    const int b = chunk * 32 + bb;
    const float* p = t + ((size_t)b * C + c) * HW;
    for (int i = threadIdx.x; i < HW; i += 256) {
      const float v = p[i];
      s1 += v; s2 += v * v;
    }
  }
#pragma unroll
  for (int off = 32; off; off >>= 1) {
    s1 += __shfl_xor(s1, off);
    s2 += __shfl_xor(s2, off);
  }
  __shared__ float red[8];
  const int lane = threadIdx.x & 63, w = threadIdx.x >> 6;
  if (lane == 0) { red[2 * w] = s1; red[2 * w + 1] = s2; }
  __syncthreads();
  if (threadIdx.x == 0) {
    atomicAdd(&sums[2 * c],     red[0] + red[2] + red[4] + red[6]);
    atomicAdd(&sums[2 * c + 1], red[1] + red[3] + red[5] + red[7]);
  }
}

__global__ void ss_k(const float* __restrict__ sums, const float* __restrict__ g,
                     const float* __restrict__ bt, float* __restrict__ ss,
                     int C, float invN)
{
  const int c = threadIdx.x;
  if (c < C) {
    const float m = sums[2 * c] * invN;
    const float var = sums[2 * c + 1] * invN - m * m;
    const float sc = g[c] * rsqrtf(var + 1e-5f);
    ss[2 * c] = sc;
    ss[2 * c + 1] = bt[c] - m * sc;
  }
}

// y = x*scale+shift per channel, then 2x2 maxpool, then relu.
template<int C, int H>
__global__ __launch_bounds__(256)
void bnpool_k(const float* __restrict__ t, const float* __restrict__ ss, float* __restrict__ r)
{
  constexpr int HP = H / 2;
  const int i = blockIdx.x * 256 + threadIdx.x;
  const int pw = i % HP;
  int tmp = i / HP;
  const int ph = tmp % HP; tmp /= HP;
  const int c = tmp % C;
  const int b = tmp / C;
  const float sc = ss[2 * c], sh = ss[2 * c + 1];
  const float* p = t + (((size_t)b * C + c) * H + ph * 2) * H + pw * 2;
  const float v0 = fmaf(p[0], sc, sh);
  const float v1 = fmaf(p[1], sc, sh);
  const float v2 = fmaf(p[H], sc, sh);
  const float v3 = fmaf(p[H + 1], sc, sh);
  r[i] = fmaxf(fmaxf(fmaxf(v0, v1), fmaxf(v2, v3)), 0.f);
}

// r1 = relu(r1 - LR*e1), vectorized
__global__ __launch_bounds__(256)
void r1up_k(float* __restrict__ r1, const float* __restrict__ e1)
{
  const int i = blockIdx.x * 256 + threadIdx.x;
  float4 r = ((const float4*)r1)[i];
  const float4 e = ((const float4*)e1)[i];
  r.x = fmaxf(fmaf(-LRr, e.x, r.x), 0.f);
  r.y = fmaxf(fmaf(-LRr, e.y, r.y), 0.f);
  r.z = fmaxf(fmaf(-LRr, e.z, r.z), 0.f);
  r.w = fmaxf(fmaf(-LRr, e.w, r.w), 0.f);
  ((float4*)r1)[i] = r;
}

extern "C" void kernel_launch(void* const* d_in, const int* in_sizes, int n_in,
                              void* d_out, int out_size, void* d_ws, size_t ws_size,
                              hipStream_t stream)
{
  const float* x  = (const float*)d_in[0];
  const float* W1 = (const float*)d_in[1];
  const float* W2 = (const float*)d_in[2];
  const float* W3 = (const float*)d_in[3];
  const float* P2 = (const float*)d_in[4];
  const float* P3 = (const float*)d_in[5];
  const float* g1 = (const float*)d_in[6];
  const float* b1 = (const float*)d_in[7];
  const float* g2 = (const float*)d_in[8];
  const float* b2 = (const float*)d_in[9];
  const float* g3 = (const float*)d_in[10];
  const float* b3 = (const float*)d_in[11];

  float* r1 = (float*)d_out;                       // [256,64,16,16]
  float* r2 = r1 + (size_t)256 * 64 * 16 * 16;     // [256,128,8,8]
  float* r3 = r2 + (size_t)256 * 128 * 8 * 8;      // [256,256,4,4]

  float* big = (float*)d_ws;                       // 16,777,216 floats, reused
  float* stats = big + (size_t)16777216;
  float* sums1 = stats;            // 128 floats (sum,sumsq interleaved)
  float* sums2 = stats + 128;      // 256
  float* sums3 = stats + 384;      // 512
  float* ss1   = stats + 896;      // 128 (scale,shift interleaved)
  float* ss2   = stats + 1024;     // 256
  float* ss3   = stats + 1280;     // 512

  hipMemsetAsync(stats, 0, 896 * sizeof(float), stream);

  // ---- feed-forward ----
  convk<32, 3, 64, 8, 16, 1, 3, EPI_RAW, false><<<8192, 256, 0, stream>>>(x, W1, big, nullptr, nullptr);
  stats_k<64, 1024><<<512, 256, 0, stream>>>(big, sums1);
  ss_k<<<1, 256, 0, stream>>>(sums1, g1, b1, ss1, 64, 1.f / 262144.f);
  bnpool_k<64, 32><<<16384, 256, 0, stream>>>(big, ss1, r1);

  convk<16, 64, 128, 8, 16, 1, 4, EPI_RAW, false><<<4096, 256, 0, stream>>>(r1, W2, big, nullptr, nullptr);
  stats_k<128, 256><<<1024, 256, 0, stream>>>(big, sums2);
  ss_k<<<1, 256, 0, stream>>>(sums2, g2, b2, ss2, 128, 1.f / 65536.f);
  bnpool_k<128, 16><<<8192, 256, 0, stream>>>(big, ss2, r2);

  convk<8, 128, 256, 8, 8, 4, 4, EPI_RAW, false><<<2048, 256, 0, stream>>>(r2, W3, big, nullptr, nullptr);
  stats_k<256, 64><<<2048, 256, 0, stream>>>(big, sums3);
  ss_k<<<1, 256, 0, stream>>>(sums3, g3, b3, ss3, 256, 1.f / 16384.f);
  bnpool_k<256, 8><<<4096, 256, 0, stream>>>(big, ss3, r3);

  // ---- predictive-coding iterations ----
  float* e1 = big;                       // [256,64,16,16]
  float* e2 = big + (size_t)4194304;     // [256,128,8,8]

  for (int it = 0; it < 10; ++it) {
    // e1 = r1 - tanh(up2(convT(r2,P2)))
    convk<8, 128, 64, 8, 8, 4, 4, EPI_E, true><<<512, 256, 0, stream>>>(r2, P2, e1, r1, nullptr);
    // e2 = r2 - tanh(up2(convT(r3,P3)))
    convk<4, 256, 128, 8, 4, 16, 4, EPI_E, true><<<256, 256, 0, stream>>>(r3, P3, e2, r2, nullptr);
    // r1 = relu(r1 - LR*e1)
    r1up_k<<<4096, 256, 0, stream>>>(r1, e1);
    // r2 = relu(r2 + LR*(-e2 + avgpool(conv(e1,W2))))
    convk<16, 64, 128, 8, 16, 1, 4, EPI_P2, false><<<4096, 256, 0, stream>>>(e1, W2, nullptr, e2, r2);
    // r3 = relu(r3 + LR*avgpool(conv(e2,W3)))
    convk<8, 128, 256, 8, 8, 4, 4, EPI_P3, false><<<2048, 256, 0, stream>>>(e2, W3, nullptr, nullptr, r3);
  }
}

// Round 2
// 1188.335 us; speedup vs baseline: 10.3120x; 10.3120x over previous
//
#include <hip/hip_runtime.h>
#include <cstddef>
#include <cstdint>

#define LRr 0.02f

typedef unsigned short u16;
typedef __attribute__((ext_vector_type(8))) __bf16 bf16x8;
typedef __attribute__((ext_vector_type(8))) short short8;
typedef __attribute__((ext_vector_type(4))) float f32x4;
typedef __attribute__((ext_vector_type(4))) u16 u16x4;

static __device__ __forceinline__ u16 f2bf(float f) {
  union { float f; unsigned int u; } v{f};
  unsigned int r = (v.u + 0x7FFFu + ((v.u >> 16) & 1u)) >> 16;
  return (u16)r;
}
static __device__ __forceinline__ float bf2f(u16 h) {
  union { unsigned int u; float f; } v{(unsigned int)h << 16};
  return v.f;
}

static __device__ __forceinline__ void gload_lds16(const void* g, void* l) {
  __builtin_amdgcn_global_load_lds(
      (const __attribute__((address_space(1))) unsigned int*)g,
      (__attribute__((address_space(3))) unsigned int*)l, 16, 0, 0);
}

enum { EP_RAW = 0, EP_E1 = 1, EP_E2 = 2, EP_P2 = 3, EP_P3 = 4 };

// Implicit-GEMM 3x3 conv, pad=1, NHWC bf16 in, per-EPI fused output.
// Block = 4 waves, 1 image (optionally split over couts or pixels via NBLK).
// A (input image + halo) staged once in LDS, XOR-swizzled; B (packed weights
// [tap][ci/8][cout][8]) double-buffered via global_load_lds per 32-k step.
template<int H, int CIN, int COUT, int WAVES_M, int WAVES_N, int WM, int WN,
         int NBLK, int EPI, bool SPLIT_M>
__global__ __launch_bounds__(256) void gemmk(
    const u16* __restrict__ in, const u16* __restrict__ wpk,
    float* __restrict__ fout, u16* __restrict__ bout,
    const u16* __restrict__ aux)
{
  constexpr int P = H * H, W = H;
  constexpr int LW = (H == 16) ? 4 : ((H == 8) ? 3 : 2);
  constexpr int M_rep = WM / 16, N_rep = WN / 16;
  constexpr int CCH = CIN / 32;
  constexpr int PW = H + 2;
  constexpr int ALDS = PW * PW * CIN * 2;
  constexpr int COB = WAVES_N * WN;
  constexpr int BSTEP = 32 * COB * 2;
  constexpr int NS = 9 * CCH;
  static_assert(SPLIT_M ? (WAVES_M * WM * NBLK == P) : (WAVES_M * WM == P), "M");
  static_assert(SPLIT_M ? (COB == COUT) : (COB * NBLK == COUT), "N");
  static_assert(ALDS + 2 * BSTEP <= 64 * 1024, "lds");

  __shared__ __align__(16) char lds[ALDS + 2 * BSTEP];

  const int tid = threadIdx.x;
  const int l = tid & 63, l15 = l & 15, lq = l >> 4;
  const int wid = tid >> 6;
  const int wn = wid % WAVES_N, wm = wid / WAVES_N;

  const int img  = (NBLK == 1) ? blockIdx.x : blockIdx.x / NBLK;
  const int half = (NBLK == 1) ? 0 : blockIdx.x % NBLK;
  const int pix0 = SPLIT_M ? half * (WAVES_M * WM) : 0;
  const int co0b = SPLIT_M ? 0 : half * COB;
  const int wm0  = pix0 + wm * WM;
  const int co   = co0b + wn * WN;

  auto stageB = [&](int buf, int step) {
    constexpr int ROUNDS = (4 * COB) / 256;
#pragma unroll
    for (int r = 0; r < ROUNDS; ++r) {
      int j = r * 256 + tid;
      int g = j / COB, c = j % COB;
      const char* gp = (const char*)wpk + ((size_t)((step * 4 + g) * COUT + co0b + c) << 4);
      char* lp = lds + ALDS + buf * BSTEP + ((r * 256 + (tid & 192)) << 4);
      gload_lds16(gp, lp);
    }
  };

  // prologue: issue B[0], zero A region, stage interior (swizzled)
  stageB(0, 0);
  for (int i = tid * 16; i < ALDS; i += 4096)
    *(int4*)(lds + i) = make_int4(0, 0, 0, 0);
  __syncthreads();
  constexpr int NCH = P * CIN / 8;
  for (int i = tid; i < NCH; i += 256) {
    int pix = i / (CIN / 8), c8 = i % (CIN / 8);
    const char* gp = (const char*)in + (((size_t)img * P + pix) * CIN + c8 * 8) * 2;
    int cell = ((pix >> LW) + 1) * PW + (pix & (W - 1)) + 1;
    int lb = ((cell * CIN + c8 * 8) << 1) ^ ((cell & 7) << 4);
    *(short8*)(lds + lb) = *(const short8*)gp;
  }
  __syncthreads();

  f32x4 acc[M_rep][N_rep];
#pragma unroll
  for (int m = 0; m < M_rep; ++m)
#pragma unroll
    for (int n = 0; n < N_rep; ++n)
#pragma unroll
      for (int r = 0; r < 4; ++r) acc[m][n][r] = 0.f;

  int ym[M_rep], xm[M_rep];
#pragma unroll
  for (int m = 0; m < M_rep; ++m) {
    int pix = wm0 + m * 16 + l15;
    ym[m] = pix >> LW;
    xm[m] = pix & (W - 1);
  }

  int step = 0, buf = 0;
  for (int tap = 0; tap < 9; ++tap) {
    const int dy = tap / 3, dx = tap % 3;
    for (int cc = 0; cc < CCH; ++cc) {
      if (step + 1 < NS) stageB(buf ^ 1, step + 1);
      bf16x8 af[M_rep], bfr[N_rep];
#pragma unroll
      for (int m = 0; m < M_rep; ++m) {
        int cell = (ym[m] + dy) * PW + xm[m] + dx;
        int lb = ((cell * CIN + cc * 32 + lq * 8) << 1) ^ ((cell & 7) << 4);
        af[m] = *(const bf16x8*)(lds + lb);
      }
#pragma unroll
      for (int n = 0; n < N_rep; ++n) {
        int lb = (lq * COB + wn * WN + n * 16 + l15) << 4;
        bfr[n] = *(const bf16x8*)(lds + ALDS + buf * BSTEP + lb);
      }
#pragma unroll
      for (int m = 0; m < M_rep; ++m)
#pragma unroll
        for (int n = 0; n < N_rep; ++n)
          acc[m][n] = __builtin_amdgcn_mfma_f32_16x16x32_bf16(af[m], bfr[n], acc[m][n], 0, 0, 0);
      __syncthreads();
      buf ^= 1;
      ++step;
    }
  }

  // ---- epilogues ----
  if constexpr (EPI == EP_RAW) {
#pragma unroll
    for (int m = 0; m < M_rep; ++m)
#pragma unroll
      for (int n = 0; n < N_rep; ++n)
#pragma unroll
        for (int r = 0; r < 4; ++r) {
          int pix = wm0 + m * 16 + lq * 4 + r;
          bout[((size_t)img * P + pix) * COUT + co + n * 16 + l15] = f2bf(acc[m][n][r]);
        }
  } else if constexpr (EPI == EP_E1) {
    // fout=r1 (RMW), bout=e1b ; result at 8x8 -> up2 to 16x16
#pragma unroll
    for (int m = 0; m < M_rep; ++m)
#pragma unroll
      for (int n = 0; n < N_rep; ++n)
#pragma unroll
        for (int r = 0; r < 4; ++r) {
          int pix = wm0 + m * 16 + lq * 4 + r;
          int y = pix >> 3, x = pix & 7;
          int cg = co + n * 16 + l15;
          float t = tanhf(acc[m][n][r]);
#pragma unroll
          for (int d2 = 0; d2 < 4; ++d2) {
            size_t idx = ((size_t)img * 256 + (2 * y + (d2 >> 1)) * 16 + 2 * x + (d2 & 1)) * 64 + cg;
            float rv = fout[idx];
            float e = rv - t;
            bout[idx] = f2bf(e);
            fout[idx] = fmaxf(rv - LRr * e, 0.f);
          }
        }
  } else if constexpr (EPI == EP_E2) {
    // fout=r2 (read-only), bout=e2b ; result 4x4 -> up2 to 8x8
#pragma unroll
    for (int n = 0; n < N_rep; ++n)
#pragma unroll
      for (int r = 0; r < 4; ++r) {
        int pix = lq * 4 + r;
        int y = pix >> 2, x = pix & 3;
        int cg = co + n * 16 + l15;
        float t = tanhf(acc[0][n][r]);
#pragma unroll
        for (int d2 = 0; d2 < 4; ++d2) {
          size_t idx = ((size_t)img * 64 + (2 * y + (d2 >> 1)) * 8 + 2 * x + (d2 & 1)) * 128 + cg;
          bout[idx] = f2bf(fout[idx] - t);
        }
      }
  } else if constexpr (EPI == EP_P2) {
    // fout=r2 (RMW), bout=r2b, aux=e2b ; pool 16x16 -> 8x8, intra-lane
#pragma unroll
    for (int m = 0; m < M_rep; m += 2)
#pragma unroll
      for (int n = 0; n < N_rep; ++n)
#pragma unroll
        for (int r0 = 0; r0 < 4; r0 += 2) {
          float sum = acc[m][n][r0] + acc[m][n][r0 + 1] + acc[m + 1][n][r0] + acc[m + 1][n][r0 + 1];
          int yo = ((wm0 >> 4) + m) >> 1;
          int xo = 2 * lq + (r0 >> 1);
          int cg = co + n * 16 + l15;
          size_t idx = ((size_t)img * 64 + yo * 8 + xo) * 128 + cg;
          float old = fout[idx];
          float d = 0.25f * sum - bf2f(aux[idx]);
          float nv = fmaxf(fmaf(LRr, d, old), 0.f);
          fout[idx] = nv;
          bout[idx] = f2bf(nv);
        }
  } else {
    // EP_P3: fout=r3 (RMW), bout=r3b ; pool 8x8 -> 4x4 via shfl_xor(32)
#pragma unroll
    for (int m = 0; m < M_rep; ++m)
#pragma unroll
      for (int n = 0; n < N_rep; ++n)
#pragma unroll
        for (int r0 = 0; r0 < 4; r0 += 2) {
          float sx = acc[m][n][r0] + acc[m][n][r0 + 1];
          float sum = sx + __shfl_xor(sx, 32);
          if (l < 32) {
            int yo = (wm0 >> 4) + m;
            int xo = 2 * (lq & 1) + (r0 >> 1);
            int cg = co + n * 16 + l15;
            size_t idx = ((size_t)img * 16 + yo * 4 + xo) * 256 + cg;
            float nv = fmaxf(fmaf(LRr, 0.25f * sum, fout[idx]), 0.f);
            fout[idx] = nv;
            bout[idx] = f2bf(nv);
          }
        }
  }
}

// pack weights -> [tap][ci/8][cout][8] bf16. FLIP: conv-transpose weights.
template<int CI, int CO, bool FLIP>
__global__ __launch_bounds__(256) void pack_k(const float* __restrict__ src, u16* __restrict__ dst) {
  int idx = blockIdx.x * 256 + threadIdx.x;
  int tap = idx / (CI * CO), rem = idx % (CI * CO);
  int ci = rem / CO, c = rem % CO;
  int dy = tap / 3, dx = tap % 3;
  float v = FLIP ? src[((size_t)ci * CO + c) * 9 + (2 - dy) * 3 + (2 - dx)]
                 : src[((size_t)c * CI + ci) * 9 + dy * 3 + dx];
  dst[(((size_t)tap * (CI / 8) + (ci >> 3)) * CO + c) * 8 + (ci & 7)] = f2bf(v);
}

// direct conv1: x NCHW fp32 [256,3,32,32] -> t1 NHWC bf16 [256,32,32,64]
__global__ __launch_bounds__(256) void conv1_k(const float* __restrict__ x,
                                               const float* __restrict__ W1,
                                               u16* __restrict__ t1) {
  __shared__ float s[972];
  const int bid = blockIdx.x;
  const int cog = bid & 7, tile = (bid >> 3) & 3, img = bid >> 5;
  const int ty0 = (tile >> 1) * 16, tx0 = (tile & 1) * 16;
  const int tid = threadIdx.x, ty = tid >> 4, tx = tid & 15;
  for (int i = tid; i < 972; i += 256) {
    int xx = i % 18, yy = (i / 18) % 18, cc = i / 324;
    int gy = ty0 + yy - 1, gx = tx0 + xx - 1;
    float v = 0.f;
    if (gy >= 0 && gy < 32 && gx >= 0 && gx < 32)
      v = x[((size_t)(img * 3 + cc) * 32 + gy) * 32 + gx];
    s[i] = v;
  }
  __syncthreads();
  float acc[8] = {};
#pragma unroll
  for (int cc = 0; cc < 3; ++cc)
#pragma unroll
    for (int dy = 0; dy < 3; ++dy)
#pragma unroll
      for (int dx = 0; dx < 3; ++dx) {
        float v = s[cc * 324 + (ty + dy) * 18 + tx + dx];
#pragma unroll
        for (int k = 0; k < 8; ++k)
          acc[k] = fmaf(v, W1[(((size_t)(cog * 8 + k) * 3 + cc) * 3 + dy) * 3 + dx], acc[k]);
      }
  short8 o;
#pragma unroll
  for (int k = 0; k < 8; ++k) o[k] = (short)f2bf(acc[k]);
  *(short8*)(t1 + ((size_t)img * 1024 + (ty0 + ty) * 32 + tx0 + tx) * 64 + cog * 8) = o;
}

// per-channel sum/sumsq over NHWC bf16
template<int C, int NPIX>
__global__ __launch_bounds__(256) void stats_k(const u16* __restrict__ t, float* __restrict__ sums) {
  constexpr int R = 256 / C;
  const int c = threadIdx.x & (C - 1);
  const int rg = threadIdx.x / C;
  float s1 = 0.f, s2 = 0.f;
  for (int p = blockIdx.x * R + rg; p < NPIX; p += 256 * R) {
    float v = bf2f(t[(size_t)p * C + c]);
    s1 += v; s2 += v * v;
  }
  __shared__ float rs[512];
  rs[threadIdx.x] = s1; rs[256 + threadIdx.x] = s2;
  __syncthreads();
  if (threadIdx.x < C) {
    for (int g = 1; g < R; ++g) {
      s1 += rs[threadIdx.x + g * C];
      s2 += rs[256 + threadIdx.x + g * C];
    }
    atomicAdd(&sums[2 * c], s1);
    atomicAdd(&sums[2 * c + 1], s2);
  }
}

__global__ void ss_k(const float* __restrict__ sums, const float* __restrict__ g,
                     const float* __restrict__ b, float* __restrict__ ss, int C, float invN) {
  int c = blockIdx.x * 64 + threadIdx.x;
  if (c < C) {
    float m = sums[2 * c] * invN;
    float var = sums[2 * c + 1] * invN - m * m;
    float sc = g[c] * rsqrtf(var + 1e-5f);
    ss[c] = sc;
    ss[C + c] = b[c] - m * sc;
  }
}

// BN affine + relu + 2x2 maxpool on NHWC bf16 -> r fp32 + rb bf16
template<int C, int H>
__global__ __launch_bounds__(256) void bnpool_k(const u16* __restrict__ t, const float* __restrict__ ss,
                                                float* __restrict__ r, u16* __restrict__ rb) {
  constexpr int HP = H / 2, C4 = C / 4;
  int idx = blockIdx.x * 256 + threadIdx.x;
  int c4 = idx % C4, po = idx / C4;
  int xo = po % HP, t2 = po / HP;
  int yo = t2 % HP, img = t2 / HP;
  const u16* p0 = t + (((size_t)img * H + 2 * yo) * H + 2 * xo) * C + c4 * 4;
  u16x4 a = *(const u16x4*)p0, b = *(const u16x4*)(p0 + C);
  u16x4 c_ = *(const u16x4*)(p0 + H * C), d = *(const u16x4*)(p0 + H * C + C);
  f32x4 sc = *(const f32x4*)(ss + c4 * 4);
  f32x4 sh = *(const f32x4*)(ss + C + c4 * 4);
  f32x4 o;
#pragma unroll
  for (int j = 0; j < 4; ++j) {
    float v0 = fmaf(bf2f(a[j]), sc[j], sh[j]);
    float v1 = fmaf(bf2f(b[j]), sc[j], sh[j]);
    float v2 = fmaf(bf2f(c_[j]), sc[j], sh[j]);
    float v3 = fmaf(bf2f(d[j]), sc[j], sh[j]);
    o[j] = fmaxf(fmaxf(fmaxf(v0, v1), fmaxf(v2, v3)), 0.f);
  }
  *(f32x4*)(r + (size_t)idx * 4) = o;
  u16x4 ob;
#pragma unroll
  for (int j = 0; j < 4; ++j) ob[j] = f2bf(o[j]);
  *(u16x4*)(rb + (size_t)idx * 4) = ob;
}

// per-image NHWC fp32 -> NCHW fp32 (LDS-tiled)
template<int P, int C>
__global__ __launch_bounds__(256) void tr_k(const float* __restrict__ in, float* __restrict__ out) {
  constexpr int TP = (P < 64) ? P : 64;
  __shared__ float tl[TP][C + 1];
  const int img = blockIdx.x;
  const float* ip = in + (size_t)img * P * C;
  float* op = out + (size_t)img * P * C;
  for (int ch = 0; ch < P / TP; ++ch) {
    __syncthreads();
    for (int i = threadIdx.x; i < TP * C; i += 256) {
      int p = i / C, c = i % C;
      tl[p][c] = ip[(size_t)(ch * TP + p) * C + c];
    }
    __syncthreads();
    for (int i = threadIdx.x; i < TP * C; i += 256) {
      int c = i / TP, p = i % TP;
      op[(size_t)c * P + ch * TP + p] = tl[p][c];
    }
  }
}

extern "C" void kernel_launch(void* const* d_in, const int* in_sizes, int n_in,
                              void* d_out, int out_size, void* d_ws, size_t ws_size,
                              hipStream_t stream) {
  const float* x  = (const float*)d_in[0];
  const float* W1 = (const float*)d_in[1];
  const float* W2 = (const float*)d_in[2];
  const float* W3 = (const float*)d_in[3];
  const float* P2 = (const float*)d_in[4];
  const float* P3 = (const float*)d_in[5];
  const float* g1 = (const float*)d_in[6];
  const float* b1 = (const float*)d_in[7];
  const float* g2 = (const float*)d_in[8];
  const float* b2 = (const float*)d_in[9];
  const float* g3 = (const float*)d_in[10];
  const float* b3 = (const float*)d_in[11];

  char* w = (char*)d_ws;
  auto alloc = [&](size_t n) { char* p = w; w += (n + 255) & ~(size_t)255; return p; };
  float* r1  = (float*)alloc(16777216);  // NHWC [256,16,16,64]
  float* r2  = (float*)alloc(8388608);   // [256,8,8,128]
  float* r3  = (float*)alloc(4194304);   // [256,4,4,256]
  u16* r1b   = (u16*)alloc(8388608);
  u16* r2b   = (u16*)alloc(4194304);
  u16* r3b   = (u16*)alloc(2097152);
  u16* W2pk  = (u16*)alloc(147456);
  u16* W3pk  = (u16*)alloc(589824);
  u16* P2pk  = (u16*)alloc(147456);
  u16* P3pk  = (u16*)alloc(589824);
  float* sums = (float*)alloc(3584);     // sums1@0(128f), sums2@128(256f), sums3@384(512f)
  float* ssb  = (float*)alloc(3584);     // ss1@0(128f),  ss2@128(256f),  ss3@384(512f)
  char* S = alloc(33554432);             // t1 bf16 32MB / t2 16MB / t3 8MB / e1b+e2b
  u16* t1 = (u16*)S;
  u16* t2 = (u16*)S;
  u16* t3 = (u16*)S;
  u16* e1b = (u16*)S;
  u16* e2b = (u16*)(S + 8388608);

  hipMemsetAsync(sums, 0, 3584, stream);

  pack_k<64, 128, false><<<288, 256, 0, stream>>>(W2, W2pk);
  pack_k<128, 256, false><<<1152, 256, 0, stream>>>(W3, W3pk);
  pack_k<128, 64, true><<<288, 256, 0, stream>>>(P2, P2pk);
  pack_k<256, 128, true><<<1152, 256, 0, stream>>>(P3, P3pk);

  // ---- feed-forward ----
  conv1_k<<<8192, 256, 0, stream>>>(x, W1, t1);
  stats_k<64, 262144><<<256, 256, 0, stream>>>(t1, sums);
  ss_k<<<1, 64, 0, stream>>>(sums, g1, b1, ssb, 64, 1.f / 262144.f);
  bnpool_k<64, 32><<<4096, 256, 0, stream>>>(t1, ssb, r1, r1b);

  gemmk<16, 64, 128, 4, 1, 64, 64, 2, EP_RAW, false><<<512, 256, 0, stream>>>(r1b, W2pk, nullptr, t2, nullptr);
  stats_k<128, 65536><<<256, 256, 0, stream>>>(t2, sums + 128);
  ss_k<<<2, 64, 0, stream>>>(sums + 128, g2, b2, ssb + 128, 128, 1.f / 65536.f);
  bnpool_k<128, 16><<<2048, 256, 0, stream>>>(t2, ssb + 128, r2, r2b);

  gemmk<8, 128, 256, 2, 2, 32, 64, 2, EP_RAW, false><<<512, 256, 0, stream>>>(r2b, W3pk, nullptr, t3, nullptr);
  stats_k<256, 16384><<<256, 256, 0, stream>>>(t3, sums + 384);
  ss_k<<<4, 64, 0, stream>>>(sums + 384, g3, b3, ssb + 384, 256, 1.f / 16384.f);
  bnpool_k<256, 8><<<1024, 256, 0, stream>>>(t3, ssb + 384, r3, r3b);

  // ---- predictive-coding iterations ----
  for (int it = 0; it < 10; ++it) {
    // e1 = r1 - tanh(up2(convT(r2,P2))) ; fused r1 = relu(r1 - LR*e1)
    gemmk<8, 128, 64, 2, 2, 16, 32, 2, EP_E1, true><<<512, 256, 0, stream>>>(r2b, P2pk, r1, e1b, nullptr);
    // e2 = r2 - tanh(up2(convT(r3,P3)))
    gemmk<4, 256, 128, 1, 4, 16, 32, 1, EP_E2, false><<<256, 256, 0, stream>>>(r3b, P3pk, r2, e2b, nullptr);
    // r2 = relu(r2 + LR*(-e2 + avgpool(conv(e1,W2))))
    gemmk<16, 64, 128, 4, 1, 64, 64, 2, EP_P2, false><<<512, 256, 0, stream>>>(e1b, W2pk, r2, r2b, e2b);
    // r3 = relu(r3 + LR*avgpool(conv(e2,W3)))
    gemmk<8, 128, 256, 2, 2, 32, 64, 2, EP_P3, false><<<512, 256, 0, stream>>>(e2b, W3pk, r3, r3b, nullptr);
  }

  // ---- NHWC -> NCHW outputs ----
  float* out = (float*)d_out;
  tr_k<256, 64><<<256, 256, 0, stream>>>(r1, out);
  tr_k<64, 128><<<256, 256, 0, stream>>>(r2, out + 4194304);
  tr_k<16, 256><<<256, 256, 0, stream>>>(r3, out + 6291456);
}

// Round 3
// 803.054 us; speedup vs baseline: 15.2593x; 1.4798x over previous
//
#include <hip/hip_runtime.h>
#include <cstddef>
#include <cstdint>

#define LRr 0.02f

typedef unsigned short u16;
typedef __attribute__((ext_vector_type(8))) __bf16 bf16x8;
typedef __attribute__((ext_vector_type(8))) short short8;
typedef __attribute__((ext_vector_type(4))) float f32x4;
typedef __attribute__((ext_vector_type(4))) u16 u16x4;

static __device__ __forceinline__ u16 f2bf(float f) {
  union { float f; unsigned int u; } v{f};
  unsigned int r = (v.u + 0x7FFFu + ((v.u >> 16) & 1u)) >> 16;
  return (u16)r;
}
static __device__ __forceinline__ float bf2f(u16 h) {
  union { unsigned int u; float f; } v{(unsigned int)h << 16};
  return v.f;
}

static __device__ __forceinline__ void gload_lds16(const void* g, void* l) {
  __builtin_amdgcn_global_load_lds(
      (const __attribute__((address_space(1))) unsigned int*)g,
      (__attribute__((address_space(3))) unsigned int*)l, 16, 0, 0);
}

enum { EP_RAW = 0, EP_E1 = 1, EP_E2 = 2, EP_P2 = 3, EP_P3 = 4 };

// Implicit-GEMM 3x3 conv, pad=1, NHWC bf16 in, per-EPI fused output.
// A (input image + halo) staged once in LDS, XOR-swizzled; B (packed weights
// [tap][ci/8][cout][8]) double-buffered via global_load_lds per 32-k step.
// STATS: accumulate per-cout sum/sumsq of fp32 results into sums[] (BN fusion).
template<int H, int CIN, int COUT, int WAVES_M, int WAVES_N, int WM, int WN,
         int NBLK, int EPI, bool SPLIT_M, bool STATS>
__device__ __forceinline__ void gemm_body(
    int bid, char* lds,
    const u16* __restrict__ in, const u16* __restrict__ wpk,
    float* __restrict__ fout, u16* __restrict__ bout,
    const u16* __restrict__ aux, float* __restrict__ sums)
{
  constexpr int P = H * H, W = H;
  constexpr int LW = (H == 16) ? 4 : ((H == 8) ? 3 : 2);
  constexpr int M_rep = WM / 16, N_rep = WN / 16;
  constexpr int CCH = CIN / 32;
  constexpr int PW = H + 2;
  constexpr int ALDS = PW * PW * CIN * 2;
  constexpr int COB = WAVES_N * WN;
  constexpr int BSTEP = 32 * COB * 2;
  constexpr int NS = 9 * CCH;
  static_assert(SPLIT_M ? (WAVES_M * WM * NBLK == P) : (WAVES_M * WM == P), "M");
  static_assert(SPLIT_M ? (COB == COUT) : (COB * NBLK == COUT), "N");
  static_assert(ALDS + 2 * BSTEP <= 64 * 1024, "lds");

  const int tid = threadIdx.x;
  const int l = tid & 63, l15 = l & 15, lq = l >> 4;
  const int wid = tid >> 6;
  const int wn = wid % WAVES_N, wm = wid / WAVES_N;

  const int img  = (NBLK == 1) ? bid : bid / NBLK;
  const int half = (NBLK == 1) ? 0 : bid % NBLK;
  const int pix0 = SPLIT_M ? half * (WAVES_M * WM) : 0;
  const int co0b = SPLIT_M ? 0 : half * COB;
  const int wm0  = pix0 + wm * WM;
  const int co   = co0b + wn * WN;

  auto stageB = [&](int buf, int step) {
    constexpr int ROUNDS = (4 * COB) / 256;
#pragma unroll
    for (int r = 0; r < ROUNDS; ++r) {
      int j = r * 256 + tid;
      int g = j / COB, c = j % COB;
      const char* gp = (const char*)wpk + ((size_t)((step * 4 + g) * COUT + co0b + c) << 4);
      char* lp = lds + ALDS + buf * BSTEP + ((r * 256 + (tid & 192)) << 4);
      gload_lds16(gp, lp);
    }
  };

  // prologue: issue B[0], zero A region, stage interior (swizzled)
  stageB(0, 0);
  for (int i = tid * 16; i < ALDS; i += 4096)
    *(int4*)(lds + i) = make_int4(0, 0, 0, 0);
  __syncthreads();
  constexpr int NCH = P * CIN / 8;
  for (int i = tid; i < NCH; i += 256) {
    int pix = i / (CIN / 8), c8 = i % (CIN / 8);
    const char* gp = (const char*)in + (((size_t)img * P + pix) * CIN + c8 * 8) * 2;
    int cell = ((pix >> LW) + 1) * PW + (pix & (W - 1)) + 1;
    int lb = ((cell * CIN + c8 * 8) << 1) ^ ((cell & 7) << 4);
    *(short8*)(lds + lb) = *(const short8*)gp;
  }
  __syncthreads();

  f32x4 acc[M_rep][N_rep];
#pragma unroll
  for (int m = 0; m < M_rep; ++m)
#pragma unroll
    for (int n = 0; n < N_rep; ++n)
#pragma unroll
      for (int r = 0; r < 4; ++r) acc[m][n][r] = 0.f;

  int ym[M_rep], xm[M_rep];
#pragma unroll
  for (int m = 0; m < M_rep; ++m) {
    int pix = wm0 + m * 16 + l15;
    ym[m] = pix >> LW;
    xm[m] = pix & (W - 1);
  }

  int step = 0, buf = 0;
  for (int tap = 0; tap < 9; ++tap) {
    const int dy = tap / 3, dx = tap % 3;
    for (int cc = 0; cc < CCH; ++cc) {
      if (step + 1 < NS) stageB(buf ^ 1, step + 1);
      bf16x8 af[M_rep], bfr[N_rep];
#pragma unroll
      for (int m = 0; m < M_rep; ++m) {
        int cell = (ym[m] + dy) * PW + xm[m] + dx;
        int lb = ((cell * CIN + cc * 32 + lq * 8) << 1) ^ ((cell & 7) << 4);
        af[m] = *(const bf16x8*)(lds + lb);
      }
#pragma unroll
      for (int n = 0; n < N_rep; ++n) {
        int lb = (lq * COB + wn * WN + n * 16 + l15) << 4;
        bfr[n] = *(const bf16x8*)(lds + ALDS + buf * BSTEP + lb);
      }
#pragma unroll
      for (int m = 0; m < M_rep; ++m)
#pragma unroll
        for (int n = 0; n < N_rep; ++n)
          acc[m][n] = __builtin_amdgcn_mfma_f32_16x16x32_bf16(af[m], bfr[n], acc[m][n], 0, 0, 0);
      __syncthreads();
      buf ^= 1;
      ++step;
    }
  }

  // ---- fused BN statistics (EP_RAW producers) ----
  if constexpr (STATS) {
    float* sbuf = (float*)lds;  // 2*COB floats, A region no longer needed
    for (int i = tid; i < 2 * COB; i += 256) sbuf[i] = 0.f;
    __syncthreads();
#pragma unroll
    for (int n = 0; n < N_rep; ++n) {
      float s1 = 0.f, s2 = 0.f;
#pragma unroll
      for (int m = 0; m < M_rep; ++m)
#pragma unroll
        for (int r = 0; r < 4; ++r) {
          float v = acc[m][n][r];
          s1 += v; s2 += v * v;
        }
      s1 += __shfl_xor(s1, 16); s2 += __shfl_xor(s2, 16);
      s1 += __shfl_xor(s1, 32); s2 += __shfl_xor(s2, 32);
      if (lq == 0) {
        int cg = wn * WN + n * 16 + l15;
        atomicAdd(&sbuf[2 * cg], s1);
        atomicAdd(&sbuf[2 * cg + 1], s2);
      }
    }
    __syncthreads();
    for (int i = tid; i < 2 * COB; i += 256) atomicAdd(&sums[2 * co0b + i], sbuf[i]);
  }

  const int gyx = 0; (void)gyx;

  // ---- epilogues ----
  if constexpr (EPI == EP_RAW) {
#pragma unroll
    for (int m = 0; m < M_rep; ++m)
#pragma unroll
      for (int n = 0; n < N_rep; ++n)
#pragma unroll
        for (int r = 0; r < 4; ++r) {
          int pix = wm0 + m * 16 + lq * 4 + r;
          bout[((size_t)img * P + pix) * COUT + co + n * 16 + l15] = f2bf(acc[m][n][r]);
        }
  } else if constexpr (EPI == EP_E1) {
    // fout=r1 (RMW), bout=e1b ; result at 8x8 -> up2 to 16x16
#pragma unroll
    for (int m = 0; m < M_rep; ++m)
#pragma unroll
      for (int n = 0; n < N_rep; ++n)
#pragma unroll
        for (int r = 0; r < 4; ++r) {
          int pix = wm0 + m * 16 + lq * 4 + r;
          int y = pix >> 3, x = pix & 7;
          int cg = co + n * 16 + l15;
          float t = tanhf(acc[m][n][r]);
#pragma unroll
          for (int d2 = 0; d2 < 4; ++d2) {
            size_t idx = ((size_t)img * 256 + (2 * y + (d2 >> 1)) * 16 + 2 * x + (d2 & 1)) * 64 + cg;
            float rv = fout[idx];
            float e = rv - t;
            bout[idx] = f2bf(e);
            fout[idx] = fmaxf(rv - LRr * e, 0.f);
          }
        }
  } else if constexpr (EPI == EP_E2) {
    // fout=r2 (read-only), bout=e2b ; result 4x4 -> up2 to 8x8
#pragma unroll
    for (int n = 0; n < N_rep; ++n)
#pragma unroll
      for (int r = 0; r < 4; ++r) {
        int pix = lq * 4 + r;
        int y = pix >> 2, x = pix & 3;
        int cg = co + n * 16 + l15;
        float t = tanhf(acc[0][n][r]);
#pragma unroll
        for (int d2 = 0; d2 < 4; ++d2) {
          size_t idx = ((size_t)img * 64 + (2 * y + (d2 >> 1)) * 8 + 2 * x + (d2 & 1)) * 128 + cg;
          bout[idx] = f2bf(fout[idx] - t);
        }
      }
  } else if constexpr (EPI == EP_P2) {
    // fout=r2 (RMW), bout=r2b, aux=e2b ; pool 16x16 -> 8x8, intra-lane
#pragma unroll
    for (int m = 0; m < M_rep; m += 2)
#pragma unroll
      for (int n = 0; n < N_rep; ++n)
#pragma unroll
        for (int r0 = 0; r0 < 4; r0 += 2) {
          float sum = acc[m][n][r0] + acc[m][n][r0 + 1] + acc[m + 1][n][r0] + acc[m + 1][n][r0 + 1];
          int yo = ((wm0 >> 4) + m) >> 1;
          int xo = 2 * lq + (r0 >> 1);
          int cg = co + n * 16 + l15;
          size_t idx = ((size_t)img * 64 + yo * 8 + xo) * 128 + cg;
          float old = fout[idx];
          float d = 0.25f * sum - bf2f(aux[idx]);
          float nv = fmaxf(fmaf(LRr, d, old), 0.f);
          fout[idx] = nv;
          bout[idx] = f2bf(nv);
        }
  } else {
    // EP_P3: fout=r3 (RMW), bout=r3b ; pool 8x8 -> 4x4 via shfl_xor(32)
#pragma unroll
    for (int m = 0; m < M_rep; ++m)
#pragma unroll
      for (int n = 0; n < N_rep; ++n)
#pragma unroll
        for (int r0 = 0; r0 < 4; r0 += 2) {
          float sx = acc[m][n][r0] + acc[m][n][r0 + 1];
          float sum = sx + __shfl_xor(sx, 32);
          if (l < 32) {
            int yo = (wm0 >> 4) + m;
            int xo = 2 * (lq & 1) + (r0 >> 1);
            int cg = co + n * 16 + l15;
            size_t idx = ((size_t)img * 16 + yo * 4 + xo) * 256 + cg;
            float nv = fmaxf(fmaf(LRr, 0.25f * sum, fout[idx]), 0.f);
            fout[idx] = nv;
            bout[idx] = f2bf(nv);
          }
        }
  }
}

// FF layer2: t2 = conv(r1b, W2) raw + stats
__global__ __launch_bounds__(256) void ff2_k(const u16* __restrict__ in, const u16* __restrict__ wpk,
                                             u16* __restrict__ outb, float* __restrict__ sums) {
  __shared__ __align__(16) char lds[49664];
  gemm_body<16, 64, 128, 4, 1, 64, 64, 2, EP_RAW, false, true>(
      blockIdx.x, lds, in, wpk, nullptr, outb, nullptr, sums);
}

// FF layer3: t3 = conv(r2b, W3) raw + stats
__global__ __launch_bounds__(256) void ff3_k(const u16* __restrict__ in, const u16* __restrict__ wpk,
                                             u16* __restrict__ outb, float* __restrict__ sums) {
  __shared__ __align__(16) char lds[41984];
  gemm_body<8, 128, 256, 2, 2, 32, 64, 2, EP_RAW, false, true>(
      blockIdx.x, lds, in, wpk, nullptr, outb, nullptr, sums);
}

// merged E1 (512 blocks) + E2 (256 blocks)
__global__ __launch_bounds__(256) void ea_k(const u16* __restrict__ r2b, const u16* __restrict__ P2pk,
                                            float* __restrict__ r1, u16* __restrict__ e1b,
                                            const u16* __restrict__ r3b, const u16* __restrict__ P3pk,
                                            const float* __restrict__ r2, u16* __restrict__ e2b) {
  __shared__ __align__(16) char lds[34816];
  if (blockIdx.x < 512)
    gemm_body<8, 128, 64, 2, 2, 16, 32, 2, EP_E1, true, false>(
        blockIdx.x, lds, r2b, P2pk, r1, e1b, nullptr, nullptr);
  else
    gemm_body<4, 256, 128, 1, 4, 16, 32, 1, EP_E2, false, false>(
        blockIdx.x - 512, lds, r3b, P3pk, (float*)r2, e2b, nullptr, nullptr);
}

// merged P2 (512 blocks) + P3 (512 blocks)
__global__ __launch_bounds__(256) void pb_k(const u16* __restrict__ e1b, const u16* __restrict__ W2pk,
                                            float* __restrict__ r2, u16* __restrict__ r2b,
                                            const u16* __restrict__ e2b, const u16* __restrict__ W3pk,
                                            float* __restrict__ r3, u16* __restrict__ r3b) {
  __shared__ __align__(16) char lds[49664];
  if (blockIdx.x < 512)
    gemm_body<16, 64, 128, 4, 1, 64, 64, 2, EP_P2, false, false>(
        blockIdx.x, lds, e1b, W2pk, r2, r2b, e2b, nullptr);
  else
    gemm_body<8, 128, 256, 2, 2, 32, 64, 2, EP_P3, false, false>(
        blockIdx.x - 512, lds, e2b, W3pk, r3, r3b, nullptr, nullptr);
}

// pack weights -> [tap][ci/8][cout][8] bf16. FLIP: conv-transpose weights.
template<int CI, int CO, bool FLIP>
__global__ __launch_bounds__(256) void pack_k(const float* __restrict__ src, u16* __restrict__ dst) {
  int idx = blockIdx.x * 256 + threadIdx.x;
  int tap = idx / (CI * CO), rem = idx % (CI * CO);
  int ci = rem / CO, c = rem % CO;
  int dy = tap / 3, dx = tap % 3;
  float v = FLIP ? src[((size_t)ci * CO + c) * 9 + (2 - dy) * 3 + (2 - dx)]
                 : src[((size_t)c * CI + ci) * 9 + dy * 3 + dx];
  dst[(((size_t)tap * (CI / 8) + (ci >> 3)) * CO + c) * 8 + (ci & 7)] = f2bf(v);
}

// direct conv1: x NCHW fp32 [256,3,32,32] -> t1 NHWC bf16 [256,32,32,64] + stats
__global__ __launch_bounds__(256) void conv1_k(const float* __restrict__ x,
                                               const float* __restrict__ W1,
                                               u16* __restrict__ t1,
                                               float* __restrict__ sums) {
  __shared__ float s[972];
  __shared__ float csum[16];
  const int bid = blockIdx.x;
  const int cog = bid & 7, tile = (bid >> 3) & 3, img = bid >> 5;
  const int ty0 = (tile >> 1) * 16, tx0 = (tile & 1) * 16;
  const int tid = threadIdx.x, ty = tid >> 4, tx = tid & 15;
  if (tid < 16) csum[tid] = 0.f;
  for (int i = tid; i < 972; i += 256) {
    int xx = i % 18, yy = (i / 18) % 18, cc = i / 324;
    int gy = ty0 + yy - 1, gx = tx0 + xx - 1;
    float v = 0.f;
    if (gy >= 0 && gy < 32 && gx >= 0 && gx < 32)
      v = x[((size_t)(img * 3 + cc) * 32 + gy) * 32 + gx];
    s[i] = v;
  }
  __syncthreads();
  float acc[8] = {};
#pragma unroll
  for (int cc = 0; cc < 3; ++cc)
#pragma unroll
    for (int dy = 0; dy < 3; ++dy)
#pragma unroll
      for (int dx = 0; dx < 3; ++dx) {
        float v = s[cc * 324 + (ty + dy) * 18 + tx + dx];
#pragma unroll
        for (int k = 0; k < 8; ++k)
          acc[k] = fmaf(v, W1[(((size_t)(cog * 8 + k) * 3 + cc) * 3 + dy) * 3 + dx], acc[k]);
      }
  // fused stats: wave-reduce each cout, LDS-combine, one global atomic per stat
#pragma unroll
  for (int k = 0; k < 8; ++k) {
    float s1 = acc[k], s2 = acc[k] * acc[k];
#pragma unroll
    for (int off = 1; off < 64; off <<= 1) {
      s1 += __shfl_xor(s1, off);
      s2 += __shfl_xor(s2, off);
    }
    if ((tid & 63) == 0) {
      atomicAdd(&csum[2 * k], s1);
      atomicAdd(&csum[2 * k + 1], s2);
    }
  }
  short8 o;
#pragma unroll
  for (int k = 0; k < 8; ++k) o[k] = (short)f2bf(acc[k]);
  *(short8*)(t1 + ((size_t)img * 1024 + (ty0 + ty) * 32 + tx0 + tx) * 64 + cog * 8) = o;
  __syncthreads();
  if (tid < 16) atomicAdd(&sums[cog * 16 + tid], csum[tid]);
}

__global__ void ss_k(const float* __restrict__ sums, const float* __restrict__ g,
                     const float* __restrict__ b, float* __restrict__ ss, int C, float invN) {
  int c = blockIdx.x * 64 + threadIdx.x;
  if (c < C) {
    float m = sums[2 * c] * invN;
    float var = sums[2 * c + 1] * invN - m * m;
    float sc = g[c] * rsqrtf(var + 1e-5f);
    ss[c] = sc;
    ss[C + c] = b[c] - m * sc;
  }
}

// BN affine + relu + 2x2 maxpool on NHWC bf16 -> r fp32 + rb bf16
template<int C, int H>
__global__ __launch_bounds__(256) void bnpool_k(const u16* __restrict__ t, const float* __restrict__ ss,
                                                float* __restrict__ r, u16* __restrict__ rb) {
  constexpr int HP = H / 2, C4 = C / 4;
  int idx = blockIdx.x * 256 + threadIdx.x;
  int c4 = idx % C4, po = idx / C4;
  int xo = po % HP, t2 = po / HP;
  int yo = t2 % HP, img = t2 / HP;
  const u16* p0 = t + (((size_t)img * H + 2 * yo) * H + 2 * xo) * C + c4 * 4;
  u16x4 a = *(const u16x4*)p0, b = *(const u16x4*)(p0 + C);
  u16x4 c_ = *(const u16x4*)(p0 + H * C), d = *(const u16x4*)(p0 + H * C + C);
  f32x4 sc = *(const f32x4*)(ss + c4 * 4);
  f32x4 sh = *(const f32x4*)(ss + C + c4 * 4);
  f32x4 o;
#pragma unroll
  for (int j = 0; j < 4; ++j) {
    float v0 = fmaf(bf2f(a[j]), sc[j], sh[j]);
    float v1 = fmaf(bf2f(b[j]), sc[j], sh[j]);
    float v2 = fmaf(bf2f(c_[j]), sc[j], sh[j]);
    float v3 = fmaf(bf2f(d[j]), sc[j], sh[j]);
    o[j] = fmaxf(fmaxf(fmaxf(v0, v1), fmaxf(v2, v3)), 0.f);
  }
  *(f32x4*)(r + (size_t)idx * 4) = o;
  u16x4 ob;
#pragma unroll
  for (int j = 0; j < 4; ++j) ob[j] = f2bf(o[j]);
  *(u16x4*)(rb + (size_t)idx * 4) = ob;
}

// per-image NHWC fp32 -> NCHW fp32 (LDS-tiled), chunk = blockIdx.y
template<int P, int C, int CHUNKS>
__global__ __launch_bounds__(256) void tr_k(const float* __restrict__ in, float* __restrict__ out) {
  constexpr int TP = P / CHUNKS;
  __shared__ float tl[TP][C + 1];
  const int img = blockIdx.x, ch = blockIdx.y;
  const float* ip = in + (size_t)img * P * C;
  float* op = out + (size_t)img * P * C;
  for (int i = threadIdx.x; i < TP * C / 4; i += 256) {
    int p = i / (C / 4), c4 = i % (C / 4);
    f32x4 v = *(const f32x4*)&ip[(size_t)(ch * TP + p) * C + c4 * 4];
#pragma unroll
    for (int j = 0; j < 4; ++j) tl[p][c4 * 4 + j] = v[j];
  }
  __syncthreads();
  for (int i = threadIdx.x; i < TP * C; i += 256) {
    int c = i / TP, p = i % TP;
    op[(size_t)c * P + ch * TP + p] = tl[p][c];
  }
}

extern "C" void kernel_launch(void* const* d_in, const int* in_sizes, int n_in,
                              void* d_out, int out_size, void* d_ws, size_t ws_size,
                              hipStream_t stream) {
  const float* x  = (const float*)d_in[0];
  const float* W1 = (const float*)d_in[1];
  const float* W2 = (const float*)d_in[2];
  const float* W3 = (const float*)d_in[3];
  const float* P2 = (const float*)d_in[4];
  const float* P3 = (const float*)d_in[5];
  const float* g1 = (const float*)d_in[6];
  const float* b1 = (const float*)d_in[7];
  const float* g2 = (const float*)d_in[8];
  const float* b2 = (const float*)d_in[9];
  const float* g3 = (const float*)d_in[10];
  const float* b3 = (const float*)d_in[11];

  char* w = (char*)d_ws;
  auto alloc = [&](size_t n) { char* p = w; w += (n + 255) & ~(size_t)255; return p; };
  float* r1  = (float*)alloc(16777216);  // NHWC [256,16,16,64]
  float* r2  = (float*)alloc(8388608);   // [256,8,8,128]
  float* r3  = (float*)alloc(4194304);   // [256,4,4,256]
  u16* r1b   = (u16*)alloc(8388608);
  u16* r2b   = (u16*)alloc(4194304);
  u16* r3b   = (u16*)alloc(2097152);
  u16* W2pk  = (u16*)alloc(147456);
  u16* W3pk  = (u16*)alloc(589824);
  u16* P2pk  = (u16*)alloc(147456);
  u16* P3pk  = (u16*)alloc(589824);
  float* sums = (float*)alloc(3584);     // sums1@0(128f), sums2@128(256f), sums3@384(512f)
  float* ssb  = (float*)alloc(3584);     // ss1@0(128f),  ss2@128(256f),  ss3@384(512f)
  char* S = alloc(33554432);             // t1 bf16 32MB / t2 16MB / t3 8MB / e1b+e2b
  u16* t1 = (u16*)S;
  u16* t2 = (u16*)S;
  u16* t3 = (u16*)S;
  u16* e1b = (u16*)S;
  u16* e2b = (u16*)(S + 8388608);

  hipMemsetAsync(sums, 0, 3584, stream);

  pack_k<64, 128, false><<<288, 256, 0, stream>>>(W2, W2pk);
  pack_k<128, 256, false><<<1152, 256, 0, stream>>>(W3, W3pk);
  pack_k<128, 64, true><<<288, 256, 0, stream>>>(P2, P2pk);
  pack_k<256, 128, true><<<1152, 256, 0, stream>>>(P3, P3pk);

  // ---- feed-forward ----
  conv1_k<<<8192, 256, 0, stream>>>(x, W1, t1, sums);
  ss_k<<<1, 64, 0, stream>>>(sums, g1, b1, ssb, 64, 1.f / 262144.f);
  bnpool_k<64, 32><<<4096, 256, 0, stream>>>(t1, ssb, r1, r1b);

  ff2_k<<<512, 256, 0, stream>>>(r1b, W2pk, t2, sums + 128);
  ss_k<<<2, 64, 0, stream>>>(sums + 128, g2, b2, ssb + 128, 128, 1.f / 65536.f);
  bnpool_k<128, 16><<<2048, 256, 0, stream>>>(t2, ssb + 128, r2, r2b);

  ff3_k<<<512, 256, 0, stream>>>(r2b, W3pk, t3, sums + 384);
  ss_k<<<4, 64, 0, stream>>>(sums + 384, g3, b3, ssb + 384, 256, 1.f / 16384.f);
  bnpool_k<256, 8><<<1024, 256, 0, stream>>>(t3, ssb + 384, r3, r3b);

  // ---- predictive-coding iterations (2 dispatches / iter) ----
  for (int it = 0; it < 10; ++it) {
    ea_k<<<768, 256, 0, stream>>>(r2b, P2pk, r1, e1b, r3b, P3pk, r2, e2b);
    pb_k<<<1024, 256, 0, stream>>>(e1b, W2pk, r2, r2b, e2b, W3pk, r3, r3b);
  }

  // ---- NHWC -> NCHW outputs ----
  float* out = (float*)d_out;
  tr_k<256, 64, 4><<<dim3(256, 4), 256, 0, stream>>>(r1, out);
  tr_k<64, 128, 1><<<dim3(256, 1), 256, 0, stream>>>(r2, out + 4194304);
  tr_k<16, 256, 1><<<dim3(256, 1), 256, 0, stream>>>(r3, out + 6291456);
}